// Round 1
// baseline (26.501 us; speedup 1.0000x reference)
//
#include <hip/hip_runtime.h>

// KGW z-score watermark detector.
// token_ids: (B, S) integer (int64 or int32 in buffer - auto-detected)
// lengths:   (B,)   integer (same dtype)
// out:       (B,)   float32 reward
//
// Per row b: for t in [CW, L): h = HASH_KEY * prod_{i=1..4}(tok[t-i]+1) mod P,
// green iff ((h*(tok[t]+1)) mod P) mod VOCAB < GREEN_SIZE.
// count -> z = (count - g*T)/sqrt(g(1-g)T), T = L-CW; reward = sigmoid((z-2)/2).

#define VOCAB 50257u
#define GREEN_SIZE 12564u
#define CW 4
#define HASH_KEY 15485863ull
#define P_MOD 2147483647ull
#define SMAX 8192

// Detect buffer element width. Values < 50257 < 2^31, so for little-endian
// int64 data every odd 32-bit word is 0. For int32 data the odd words are
// random tokens (all-zero probability ~ 50257^-1024 == never).
__global__ void kgw_detect_dtype(const unsigned int* __restrict__ w,
                                 int* __restrict__ flag) {
    __shared__ int any_nz;
    if (threadIdx.x == 0) any_nz = 0;
    __syncthreads();
    int local = 0;
    for (int i = threadIdx.x; i < 1024; i += blockDim.x)
        if (w[2 * i + 1] != 0u) local = 1;
    if (local) atomicOr(&any_nz, 1);
    __syncthreads();
    if (threadIdx.x == 0) *flag = any_nz ? 0 : 1;   // 1 -> int64 layout
}

__global__ __launch_bounds__(256) void kgw_kernel(
        const void* __restrict__ tokens, const void* __restrict__ lengths,
        float* __restrict__ out, const int* __restrict__ flag, int S) {
    __shared__ int s_tok[SMAX];
    __shared__ int s_wsum[4];

    const int b   = blockIdx.x;
    const int tid = threadIdx.x;
    const int is64 = *flag;   // uniform

    long long L;
    if (is64) L = ((const long long*)lengths)[b];
    else      L = (long long)((const int*)lengths)[b];
    const int Li = (int)L;

    if (Li < CW + 1) {                 // uniform branch per block
        if (tid == 0) out[b] = 0.0f;
        return;
    }

    // Stage tok[0..L) + 1 into LDS (coalesced).
    if (is64) {
        const long long* tp = (const long long*)tokens + (size_t)b * (size_t)S;
        for (int t = tid; t < Li; t += 256) s_tok[t] = (int)tp[t] + 1;
    } else {
        const int* tp = (const int*)tokens + (size_t)b * (size_t)S;
        for (int t = tid; t < Li; t += 256) s_tok[t] = tp[t] + 1;
    }
    __syncthreads();

    int cnt = 0;
    for (int t = CW + tid; t < Li; t += 256) {
        unsigned long long h = HASH_KEY;
        h = (h * (unsigned long long)s_tok[t - 1]) % P_MOD;
        h = (h * (unsigned long long)s_tok[t - 2]) % P_MOD;
        h = (h * (unsigned long long)s_tok[t - 3]) % P_MOD;
        h = (h * (unsigned long long)s_tok[t - 4]) % P_MOD;
        unsigned long long g = (h * (unsigned long long)s_tok[t]) % P_MOD;
        cnt += ((unsigned int)(g % VOCAB) < GREEN_SIZE) ? 1 : 0;
    }

    // Wave(64) shuffle reduce, then cross-wave via LDS.
    for (int off = 32; off > 0; off >>= 1) cnt += __shfl_down(cnt, off, 64);
    const int lane = tid & 63, wave = tid >> 6;
    if (lane == 0) s_wsum[wave] = cnt;
    __syncthreads();

    if (tid == 0) {
        const float count = (float)(s_wsum[0] + s_wsum[1] + s_wsum[2] + s_wsum[3]);
        const float T = (float)(Li - CW);                 // >= 1 here
        const float z = (count - 0.25f * T) / sqrtf(0.1875f * T);
        const float x = (z - 2.0f) * 0.5f;
        out[b] = 1.0f / (1.0f + expf(-x));
    }
}

extern "C" void kernel_launch(void* const* d_in, const int* in_sizes, int n_in,
                              void* d_out, int out_size, void* d_ws, size_t ws_size,
                              hipStream_t stream) {
    const void* tokens  = d_in[0];
    const void* lengths = d_in[1];
    float* out = (float*)d_out;
    int* flag  = (int*)d_ws;

    const int B = out_size;               // 512
    const int S = in_sizes[0] / B;        // 8192

    kgw_detect_dtype<<<1, 256, 0, stream>>>((const unsigned int*)tokens, flag);
    kgw_kernel<<<B, 256, 0, stream>>>(tokens, lengths, out, flag, S);
}

// Round 2
// 15.012 us; speedup vs baseline: 1.7653x; 1.7653x over previous
//
#include <hip/hip_runtime.h>

// KGW z-score watermark detector — single fused kernel.
// token_ids: (B, S) integer (int64 or int32 buffer — auto-detected per block)
// lengths:   (B,)   integer (same dtype)
// out:       (B,)   float32 reward
//
// Per row b: for t in [CW, L): h = HASH_KEY * prod_{i=1..4}(tok[t-i]+1) mod P,
// green iff ((h*(tok[t]+1)) mod P) mod VOCAB < GREEN_SIZE.
// count -> z = (count - g*T)/sqrt(g(1-g)T), T = L-CW; reward = sigmoid((z-2)/2).

#define VOCAB 50257u
#define GREEN_SIZE 12564u
#define CW 4
#define HASH_KEY 15485863u      // == 15485863 % P, fits 31 bits
#define P31 2147483647u         // 2^31 - 1 (Mersenne prime)
#define SMAX 8192

// a < 2^31, b < 2^31  ->  (a*b) mod (2^31-1), via Mersenne fold (2^31 === 1 mod P).
__device__ __forceinline__ unsigned int mulmodP(unsigned int a, unsigned int b) {
    unsigned long long x = (unsigned long long)a * (unsigned long long)b; // < 2^62
    unsigned int y = (unsigned int)(x & P31) + (unsigned int)(x >> 31);   // <= 2^32-2
    y = (y & P31) + (y >> 31);                                            // <= P+1
    if (y >= P31) y -= P31;
    return y;
}

__global__ __launch_bounds__(256) void kgw_fused(
        const void* __restrict__ tokens, const void* __restrict__ lengths,
        float* __restrict__ out, int S) {
    __shared__ int s_tok[SMAX];
    __shared__ int s_red[4];
    __shared__ int s_any;

    const int b   = blockIdx.x;
    const int tid = threadIdx.x;

    // --- dtype detection (per block, from first 2KB — safe in both layouts).
    // int64 data: values < 50257 so every odd 32-bit word is 0.
    // int32 data: odd words are random tokens; 256 all-zero ~ never.
    if (tid == 0) s_any = 0;
    __syncthreads();
    if (((const unsigned int*)tokens)[2 * tid + 1] != 0u) atomicOr(&s_any, 1);
    __syncthreads();
    const int is64 = (s_any == 0);   // uniform

    long long L;
    if (is64) L = ((const long long*)lengths)[b];
    else      L = (long long)((const int*)lengths)[b];
    const int Li = (int)L;

    if (Li < CW + 1) {               // uniform per block
        if (tid == 0) out[b] = 0.0f;
        return;
    }

    // --- stage tok[0..Li) + 1 into LDS (16B vector loads).
    if (is64) {
        const longlong2* tp2 = (const longlong2*)((const long long*)tokens + (size_t)b * (size_t)S);
        const int npair = Li >> 1;
        for (int i = tid; i < npair; i += 256) {
            longlong2 v = tp2[i];
            s_tok[2 * i]     = (int)v.x + 1;
            s_tok[2 * i + 1] = (int)v.y + 1;
        }
        if ((Li & 1) && tid == 0)
            s_tok[Li - 1] = (int)((const long long*)tokens)[(size_t)b * (size_t)S + Li - 1] + 1;
    } else {
        const int* tp = (const int*)tokens + (size_t)b * (size_t)S;
        const int nq = Li >> 2;
        const int4* tp4 = (const int4*)tp;
        for (int i = tid; i < nq; i += 256) {
            int4 v = tp4[i];
            s_tok[4 * i]     = v.x + 1;
            s_tok[4 * i + 1] = v.y + 1;
            s_tok[4 * i + 2] = v.z + 1;
            s_tok[4 * i + 3] = v.w + 1;
        }
        for (int t = 4 * nq + tid; t < Li; t += 256) s_tok[t] = tp[t] + 1;
    }
    __syncthreads();

    // --- score tokens [CW, Li).
    int cnt = 0;
    for (int t = CW + tid; t < Li; t += 256) {
        unsigned int h = HASH_KEY;
        h = mulmodP(h, (unsigned int)s_tok[t - 1]);
        h = mulmodP(h, (unsigned int)s_tok[t - 2]);
        h = mulmodP(h, (unsigned int)s_tok[t - 3]);
        h = mulmodP(h, (unsigned int)s_tok[t - 4]);
        unsigned int g = mulmodP(h, (unsigned int)s_tok[t]);
        cnt += ((g % VOCAB) < GREEN_SIZE) ? 1 : 0;
    }

    // --- reduce: wave64 shuffle, then cross-wave via LDS.
    for (int off = 32; off > 0; off >>= 1) cnt += __shfl_down(cnt, off, 64);
    const int lane = tid & 63, wave = tid >> 6;
    if (lane == 0) s_red[wave] = cnt;
    __syncthreads();

    if (tid == 0) {
        const float count = (float)(s_red[0] + s_red[1] + s_red[2] + s_red[3]);
        const float T = (float)(Li - CW);                  // >= 1 here
        const float z = (count - 0.25f * T) / sqrtf(0.1875f * T);
        const float x = (z - 2.0f) * 0.5f;
        out[b] = 1.0f / (1.0f + expf(-x));
    }
}

extern "C" void kernel_launch(void* const* d_in, const int* in_sizes, int n_in,
                              void* d_out, int out_size, void* d_ws, size_t ws_size,
                              hipStream_t stream) {
    const void* tokens  = d_in[0];
    const void* lengths = d_in[1];
    float* out = (float*)d_out;

    const int B = out_size;               // 512
    const int S = in_sizes[0] / B;        // 8192

    kgw_fused<<<B, 256, 0, stream>>>(tokens, lengths, out, S);
}